// Round 1
// baseline (944.782 us; speedup 1.0000x reference)
//
#include <hip/hip_runtime.h>

// SS2D / VMamba block, fp32 end-to-end.
// B=2, H=W=56, L=3136, D_MODEL=192, D_INNER=384, N=16, K=4, DT_RANK=12.
//
// Key identity: xs[b,k,d,t] = xi[b,d,f_k(t)] with f_k a bijection, so all
// per-position projections are computed indexed by flat pixel f; only the
// scan walks in direction order, and it atomically accumulates its output
// at flat position f_k(t) into y0 (pre-initialized with u * sum_k D[k,d]).
//
// Workspace (floats):
//   x1      @ 0         (B,L,192)   1,204,224
//   xiraw   @ 1204224   (B,384,L)   2,408,448   -> reused as gbuf after dwconv
//   z       @ 3612672   (B,L,384)   2,408,448
//   xi      @ 6021120   (B,384,L)   2,408,448
//   xdbl    @ 8429568   (B,K,44,L)  1,103,872
//   delta   @ 9533440   (B,K,384,L) 9,633,792   -> reused as y2 after scan
//   y0      @ 19167232  (B,L,384)   2,408,448
// total 21,575,680 floats = 86.3 MB  (requires ws_size >= that)

#define LPIX 3136
#define HH 56

__device__ __forceinline__ float gelu_f(float x) {
    return 0.5f * x * (1.0f + erff(x * 0.70710678118654752f));
}

// ---------------- shared fp32 GEMM: C = A * W^T (tiles 64x64, BK=32) --------
// A row-major (M,Kd) except MODE 3 (planar (B,96,L)). W row-major (N,Kd).
// MODE 0: o<384 -> out0 planar (B,384,L) [xi_raw]; o>=384 -> out1 (M,384) [z]
// MODE 1: out0 row-major (M,N)
// MODE 2: A_eff = A + A2 (residual); gelu(v+bias) -> planar (B,96,L) [final out]
// MODE 3: A planar (B,96,L); gelu(v+bias) -> row-major (M,N) [x1]
template <int MODE>
__global__ __launch_bounds__(256) void gemm_k(
    const float* __restrict__ A, const float* __restrict__ A2,
    const float* __restrict__ W, const float* __restrict__ bias,
    float* __restrict__ out0, float* __restrict__ out1,
    int M, int N, int Kd)
{
    __shared__ __align__(16) float As[32][68];
    __shared__ __align__(16) float Ws[32][68];
    const int tid = threadIdx.x;
    const int m0 = blockIdx.x * 64;
    const int n0 = blockIdx.y * 64;
    const int mi = tid >> 4, ni = tid & 15;
    float acc[4][4] = {};

    for (int k0 = 0; k0 < Kd; k0 += 32) {
        #pragma unroll
        for (int p = 0; p < 2; ++p) {
            int r = (tid >> 3) + p * 32;
            int kv = (tid & 7) * 4;
            int m = m0 + r;
            float4 v;
            if constexpr (MODE == 3) {
                int b = m / LPIX, l = m % LPIX;
                const float* px = A + ((size_t)(b * 96 + k0 + kv)) * LPIX + l;
                v.x = px[0]; v.y = px[LPIX]; v.z = px[2 * LPIX]; v.w = px[3 * LPIX];
            } else {
                v = *reinterpret_cast<const float4*>(A + (size_t)m * Kd + k0 + kv);
                if constexpr (MODE == 2) {
                    float4 r2 = *reinterpret_cast<const float4*>(A2 + (size_t)m * Kd + k0 + kv);
                    v.x += r2.x; v.y += r2.y; v.z += r2.z; v.w += r2.w;
                }
            }
            As[kv + 0][r] = v.x; As[kv + 1][r] = v.y;
            As[kv + 2][r] = v.z; As[kv + 3][r] = v.w;
        }
        #pragma unroll
        for (int p = 0; p < 2; ++p) {
            int r = (tid >> 3) + p * 32;
            int kv = (tid & 7) * 4;
            int n = n0 + r;
            float4 v = make_float4(0.f, 0.f, 0.f, 0.f);
            if (n < N) v = *reinterpret_cast<const float4*>(W + (size_t)n * Kd + k0 + kv);
            Ws[kv + 0][r] = v.x; Ws[kv + 1][r] = v.y;
            Ws[kv + 2][r] = v.z; Ws[kv + 3][r] = v.w;
        }
        __syncthreads();
        #pragma unroll
        for (int kk = 0; kk < 32; ++kk) {
            float4 a = *reinterpret_cast<const float4*>(&As[kk][mi * 4]);
            float4 b = *reinterpret_cast<const float4*>(&Ws[kk][ni * 4]);
            float av[4] = {a.x, a.y, a.z, a.w};
            float bv[4] = {b.x, b.y, b.z, b.w};
            #pragma unroll
            for (int i = 0; i < 4; ++i)
                #pragma unroll
                for (int j = 0; j < 4; ++j)
                    acc[i][j] = fmaf(av[i], bv[j], acc[i][j]);
        }
        __syncthreads();
    }

    #pragma unroll
    for (int i = 0; i < 4; ++i) {
        int m = m0 + mi * 4 + i;
        int b = m / LPIX, l = m % LPIX;
        #pragma unroll
        for (int j = 0; j < 4; ++j) {
            int o = n0 + ni * 4 + j;
            float v = acc[i][j];
            if constexpr (MODE == 0) {
                if (o < 384) out0[((size_t)(b * 384 + o)) * LPIX + l] = v;
                else         out1[(size_t)m * 384 + (o - 384)] = v;
            } else if constexpr (MODE == 1) {
                out0[(size_t)m * N + o] = v;
            } else if constexpr (MODE == 2) {
                if (o < N) out0[((size_t)(b * 96 + o)) * LPIX + l] = gelu_f(v + bias[o]);
            } else {
                out0[(size_t)m * N + o] = gelu_f(v + bias[o]);
            }
        }
    }
}

// ---------------- depthwise 3x3 SAME + bias + SiLU --------------------------
__global__ __launch_bounds__(256) void dwconv_k(
    const float* __restrict__ xin, const float* __restrict__ w9,
    const float* __restrict__ bias, float* __restrict__ xout)
{
    int f = blockIdx.x * 256 + threadIdx.x;
    if (f >= LPIX) return;
    int c = blockIdx.y, b = blockIdx.z;
    const float* p = xin + ((size_t)b * 384 + c) * LPIX;
    int h = f / HH, w = f % HH;
    float s = bias[c];
    #pragma unroll
    for (int dh = -1; dh <= 1; ++dh) {
        int h2 = h + dh;
        if ((unsigned)h2 >= HH) continue;
        #pragma unroll
        for (int dw = -1; dw <= 1; ++dw) {
            int w2 = w + dw;
            if ((unsigned)w2 >= HH) continue;
            s = fmaf(p[h2 * HH + w2], w9[c * 9 + (dh + 1) * 3 + (dw + 1)], s);
        }
    }
    xout[((size_t)b * 384 + c) * LPIX + f] = s / (1.f + __expf(-s));
}

// ---------------- x_proj: xdbl[b,k,c,f] = sum_d xpw[k,c,d]*xi[b,d,f] --------
__global__ __launch_bounds__(256) void xproj_k(
    const float* __restrict__ xi, const float* __restrict__ xpw,
    float* __restrict__ xdbl)
{
    __shared__ float XI[64][64];
    __shared__ float WS[44][64];
    int f0 = blockIdx.x * 64;
    int k = blockIdx.y, b = blockIdx.z;
    int tid = threadIdx.x;
    int tx = tid & 63, ty = tid >> 6;
    float acc[11] = {};
    for (int d0 = 0; d0 < 384; d0 += 64) {
        __syncthreads();
        #pragma unroll
        for (int i = 0; i < 16; ++i) {
            int idx = tid + i * 256;
            int dl = idx >> 6, fl = idx & 63;
            XI[dl][fl] = xi[((size_t)b * 384 + d0 + dl) * LPIX + f0 + fl];
        }
        #pragma unroll
        for (int i = 0; i < 11; ++i) {
            int idx = tid + i * 256;
            int cc = idx >> 6, dd = idx & 63;
            WS[cc][dd] = xpw[((size_t)k * 44 + cc) * 384 + d0 + dd];
        }
        __syncthreads();
        for (int dd = 0; dd < 64; ++dd) {
            float xv = XI[dd][tx];
            #pragma unroll
            for (int j = 0; j < 11; ++j)
                acc[j] = fmaf(WS[ty * 11 + j][dd], xv, acc[j]);
        }
    }
    #pragma unroll
    for (int j = 0; j < 11; ++j) {
        int c = ty * 11 + j;
        xdbl[(((size_t)b * 4 + k) * 44 + c) * LPIX + f0 + tx] = acc[j];
    }
}

// ---------------- dt_proj + softplus: delta[b,k,d,f] ------------------------
__global__ __launch_bounds__(256) void dtproj_k(
    const float* __restrict__ xdbl, const float* __restrict__ dtw,
    const float* __restrict__ dtb, float* __restrict__ delta)
{
    int f = blockIdx.x * 256 + threadIdx.x;
    if (f >= LPIX) return;
    int d0 = blockIdx.y * 8;
    int bk = blockIdx.z;
    int k = bk & 3;
    const float* px = xdbl + (size_t)bk * 44 * LPIX + f;
    float xv[12];
    #pragma unroll
    for (int r = 0; r < 12; ++r) xv[r] = px[(size_t)r * LPIX];
    #pragma unroll
    for (int dd = 0; dd < 8; ++dd) {
        int d = d0 + dd;
        const float* pw = dtw + ((size_t)k * 384 + d) * 12;
        float s = dtb[k * 384 + d];
        #pragma unroll
        for (int r = 0; r < 12; ++r) s = fmaf(pw[r], xv[r], s);
        s = (s > 20.f) ? s : log1pf(__expf(s));
        delta[((size_t)bk * 384 + d) * LPIX + f] = s;
    }
}

// ---------------- init y0[b,f,d] = xi[b,d,f] * sum_k Ds[k,d] (transpose) ----
__global__ __launch_bounds__(256) void inity_k(
    const float* __restrict__ xi, const float* __restrict__ Ds,
    float* __restrict__ y0)
{
    __shared__ float T[64][65];
    int f0 = blockIdx.x * 64, d0 = blockIdx.y * 64, b = blockIdx.z;
    int tid = threadIdx.x;
    #pragma unroll
    for (int i = 0; i < 16; ++i) {
        int idx = tid + i * 256;
        int dl = idx >> 6, fl = idx & 63;
        T[dl][fl] = xi[((size_t)b * 384 + d0 + dl) * LPIX + f0 + fl];
    }
    __syncthreads();
    #pragma unroll
    for (int i = 0; i < 16; ++i) {
        int idx = tid + i * 256;
        int fl = idx >> 6, dl = idx & 63;
        int d = d0 + dl;
        float sD = Ds[d] + Ds[384 + d] + Ds[768 + d] + Ds[1152 + d];
        y0[((size_t)b * LPIX + f0 + fl) * 384 + d] = T[dl][fl] * sD;
    }
}

// ---------------- selective scan -------------------------------------------
// 1 wave per (b,k,4 consecutive d); lane = 16*g + n  (g: which d, n: state).
// 8-step ping-pong register prefetch to cover L2/L3 load latency at the
// very low occupancy (768 waves total).
__global__ __launch_bounds__(64) void scan_k(
    const float* __restrict__ delta, const float* __restrict__ xi,
    const float* __restrict__ xdbl, const float* __restrict__ A_log,
    float* __restrict__ y0)
{
    const int wid = blockIdx.x;               // 0..767
    const int b = wid / 384;
    const int k = (wid / 96) & 3;
    const int lane = threadIdx.x;
    const int g = lane >> 4, n = lane & 15;
    const int d = (wid % 96) * 4 + g;

    const float Aneg = -__expf(A_log[((size_t)k * 384 + d) * 16 + n]);
    const float* pD = delta + (((size_t)b * 4 + k) * 384 + d) * LPIX;
    const float* pU = xi + ((size_t)b * 384 + d) * LPIX;
    const float* pB = xdbl + (((size_t)b * 4 + k) * 44 + 12 + n) * LPIX;
    const float* pC = xdbl + (((size_t)b * 4 + k) * 44 + 28 + n) * LPIX;
    float* pY = y0 + (size_t)b * LPIX * 384 + d;

    float h = 0.f;
    struct SV { float dl, u, Bv, Cv; int f; };
    SV bA[8], bB[8];

    auto f_of = [&](int t) -> int {
        if (k == 0) return t;
        if (k == 1) return (t % HH) * HH + (t / HH);
        if (k == 2) return LPIX - 1 - t;
        int u2 = LPIX - 1 - t;
        return (u2 % HH) * HH + (u2 / HH);
    };
    auto ld = [&](int t, SV& s) {
        int f = f_of(t);
        s.f = f;
        s.dl = pD[f]; s.u = pU[f]; s.Bv = pB[f]; s.Cv = pC[f];
    };
    auto step = [&](const SV& s) {
        float a = __expf(s.dl * Aneg);
        float duB = s.dl * s.u * s.Bv;
        h = fmaf(a, h, duB);
        float p = h * s.Cv;
        // sum over the 16 lanes of the group via DPP row_shr (lane n==15 gets it)
        p += __int_as_float(__builtin_amdgcn_update_dpp(0, __float_as_int(p), 0x111, 0xf, 0xf, true));
        p += __int_as_float(__builtin_amdgcn_update_dpp(0, __float_as_int(p), 0x112, 0xf, 0xf, true));
        p += __int_as_float(__builtin_amdgcn_update_dpp(0, __float_as_int(p), 0x114, 0xf, 0xf, true));
        p += __int_as_float(__builtin_amdgcn_update_dpp(0, __float_as_int(p), 0x118, 0xf, 0xf, true));
        if (n == 15)
            __hip_atomic_fetch_add(pY + (size_t)s.f * 384, p,
                                   __ATOMIC_RELAXED, __HIP_MEMORY_SCOPE_AGENT);
    };

    #pragma unroll
    for (int j = 0; j < 8; ++j) ld(j, bA[j]);
    for (int t0 = 0; t0 < LPIX; t0 += 16) {
        #pragma unroll
        for (int j = 0; j < 8; ++j) ld(t0 + 8 + j, bB[j]);
        #pragma unroll
        for (int j = 0; j < 8; ++j) step(bA[j]);
        if (t0 + 16 < LPIX) {
            #pragma unroll
            for (int j = 0; j < 8; ++j) ld(t0 + 16 + j, bA[j]);
        }
        #pragma unroll
        for (int j = 0; j < 8; ++j) step(bB[j]);
    }
}

// ---------------- LayerNorm + SiLU gate -------------------------------------
__global__ __launch_bounds__(256) void lngate_k(
    const float* __restrict__ y0, const float* __restrict__ z,
    const float* __restrict__ lng, const float* __restrict__ lnb,
    float* __restrict__ gbuf)
{
    int m = blockIdx.x * 4 + (threadIdx.x >> 6);
    int lane = threadIdx.x & 63;
    const float* py = y0 + (size_t)m * 384;
    float v[6];
    float s = 0.f, sq = 0.f;
    #pragma unroll
    for (int i = 0; i < 6; ++i) {
        v[i] = py[lane + i * 64];
        s += v[i]; sq += v[i] * v[i];
    }
    #pragma unroll
    for (int off = 1; off < 64; off <<= 1) {
        s += __shfl_xor(s, off);
        sq += __shfl_xor(sq, off);
    }
    float mu = s * (1.f / 384.f);
    float var = sq * (1.f / 384.f) - mu * mu;
    float rs = rsqrtf(var + 1e-5f);
    const float* pz = z + (size_t)m * 384;
    float* pg = gbuf + (size_t)m * 384;
    #pragma unroll
    for (int i = 0; i < 6; ++i) {
        int c = lane + i * 64;
        float nv = (v[i] - mu) * rs * lng[c] + lnb[c];
        float zv = pz[c];
        pg[c] = nv * (zv / (1.f + __expf(-zv)));
    }
}

// ---------------- host side -------------------------------------------------
extern "C" void kernel_launch(void* const* d_in, const int* in_sizes, int n_in,
                              void* d_out, int out_size, void* d_ws, size_t ws_size,
                              hipStream_t stream) {
    const float* x        = (const float*)d_in[0];
    const float* w_init   = (const float*)d_in[1];
    const float* b_init   = (const float*)d_in[2];
    const float* w_inproj = (const float*)d_in[3];
    const float* w_conv   = (const float*)d_in[4];
    const float* b_conv   = (const float*)d_in[5];
    const float* w_xproj  = (const float*)d_in[6];
    const float* w_dt     = (const float*)d_in[7];
    const float* b_dt     = (const float*)d_in[8];
    const float* A_log    = (const float*)d_in[9];
    const float* Ds       = (const float*)d_in[10];
    const float* ln_g     = (const float*)d_in[11];
    const float* ln_b     = (const float*)d_in[12];
    const float* w_out    = (const float*)d_in[13];
    const float* w_fina   = (const float*)d_in[14];
    const float* b_fina   = (const float*)d_in[15];

    float* ws    = (float*)d_ws;
    float* x1    = ws + 0;
    float* xiraw = ws + 1204224;   // later reused as gbuf
    float* z     = ws + 3612672;
    float* xi    = ws + 6021120;
    float* xdbl  = ws + 8429568;
    float* delta = ws + 9533440;   // later reused as y2
    float* y0    = ws + 19167232;
    float* out   = (float*)d_out;

    // 1) x1 = gelu(conv_init(x))                 (B,L,192)
    gemm_k<3><<<dim3(98, 3), 256, 0, stream>>>(x, nullptr, w_init, b_init,
                                               x1, nullptr, 6272, 192, 96);
    // 2) in_proj -> xi_raw planar + z
    gemm_k<0><<<dim3(98, 12), 256, 0, stream>>>(x1, nullptr, w_inproj, nullptr,
                                                xiraw, z, 6272, 768, 192);
    // 3) depthwise 3x3 + SiLU -> xi planar
    dwconv_k<<<dim3(13, 384, 2), 256, 0, stream>>>(xiraw, w_conv, b_conv, xi);
    // 4) x_proj -> xdbl (rows 0-11 dt, 12-27 B, 28-43 C)
    xproj_k<<<dim3(49, 4, 2), 256, 0, stream>>>(xi, w_xproj, xdbl);
    // 5) dt_proj + softplus -> delta
    dtproj_k<<<dim3(13, 48, 8), 256, 0, stream>>>(xdbl, w_dt, b_dt, delta);
    // 6) y0[b,f,d] = xi * sum_k D  (also clears the 0xAA poison)
    inity_k<<<dim3(49, 6, 2), 256, 0, stream>>>(xi, Ds, y0);
    // 7) 4-direction selective scan, atomic accumulate into y0
    scan_k<<<768, 64, 0, stream>>>(delta, xi, xdbl, A_log, y0);
    // 8) LayerNorm + SiLU(z) gate -> gbuf (reuses xiraw)
    lngate_k<<<1568, 256, 0, stream>>>(y0, z, ln_g, ln_b, xiraw);
    // 9) out_proj -> y2 (reuses delta)
    gemm_k<1><<<dim3(98, 3), 256, 0, stream>>>(xiraw, nullptr, w_out, nullptr,
                                               delta, nullptr, 6272, 192, 384);
    // 10) final: gelu(conv_fina(y2 + x1)) -> out planar (B,96,56,56)
    gemm_k<2><<<dim3(98, 2), 256, 0, stream>>>(delta, x1, w_fina, b_fina,
                                               out, nullptr, 6272, 96, 192);
}

// Round 2
// 568.657 us; speedup vs baseline: 1.6614x; 1.6614x over previous
//
#include <hip/hip_runtime.h>

// SS2D / VMamba block, fp32. Round 2: segmented scan (16 segments) +
// scan-order operand layouts (everything the scan touches is contiguous).
//
// B=2, H=W=56, L=3136, D_MODEL=192, D_INNER=384, N=16, K=4, DT_RANK=12.
//
// Workspace layout (float offsets):
//   x1    @ 0          (B,L,192)    1,204,224
//   z     @ 1204224    (B,L,384)    2,408,448
//   xiR   @ 3612672    (B,L,384)    2,408,448   raster t-major   -> gbuf later
//   xiT   @ 6021120    (B,L,384)    2,408,448   transposed t-major
//   xdblT @ 8429568    (B,4,L,44)   1,103,872   dt rows 0-11, B 12-27, C 28-43
//   dT    @ 9533440    (B,4,L,384)  9,633,792   delta, scan order -> y2 later
//     (xiraw planar 2.4M @9533440 and xi planar 2.4M @11941888 live here
//      transiently before dT is written)
//   y0    @ 19167232   (B,L,384)    2,408,448
//   lh    @ 21575680   (SEG,8,384,16) 786,432
//   Pb    @ 22362112   (SEG,8,384,16) 786,432
// total 23,148,544 floats = 92.6 MB

#define LPIX 3136
#define HH 56
#define SEG 16
#define SEGLEN 196

__device__ __forceinline__ float gelu_f(float x) {
    return 0.5f * x * (1.0f + erff(x * 0.70710678118654752f));
}

__device__ __forceinline__ float dpp_shr_sum16(float p) {
    p += __int_as_float(__builtin_amdgcn_update_dpp(0, __float_as_int(p), 0x111, 0xf, 0xf, true));
    p += __int_as_float(__builtin_amdgcn_update_dpp(0, __float_as_int(p), 0x112, 0xf, 0xf, true));
    p += __int_as_float(__builtin_amdgcn_update_dpp(0, __float_as_int(p), 0x114, 0xf, 0xf, true));
    p += __int_as_float(__builtin_amdgcn_update_dpp(0, __float_as_int(p), 0x118, 0xf, 0xf, true));
    return p;
}

// ---------------- shared fp32 GEMM: C = A * W^T (tiles 64x64, BK=32) --------
// MODE 0: o<384 -> out0 planar (B,384,L); o>=384 -> out1 (M,384) [z]
// MODE 1: out0 row-major (M,N)
// MODE 2: A_eff = A + A2; gelu(v+bias) -> planar (B,96,L) [final out]
// MODE 3: A planar (B,96,L); gelu(v+bias) -> row-major (M,N) [x1]
// MODE 4: x_proj: A=(xiR), A2=(xiT), pick by blockIdx.z&1; W=xpw[k]; out
//         xdblT[b,k,t,44] (N=44, masked)
template <int MODE>
__global__ __launch_bounds__(256) void gemm_k(
    const float* __restrict__ A, const float* __restrict__ A2,
    const float* __restrict__ W, const float* __restrict__ bias,
    float* __restrict__ out0, float* __restrict__ out1,
    int M, int N, int Kd)
{
    __shared__ __align__(16) float As[32][68];
    __shared__ __align__(16) float Ws[32][68];
    const int tid = threadIdx.x;
    const int m0 = blockIdx.x * 64;
    const int n0 = blockIdx.y * 64;
    const int kz = blockIdx.z;
    const int mi = tid >> 4, ni = tid & 15;
    const float* Ause = A;
    if constexpr (MODE == 4) {
        if (kz & 1) Ause = A2;
        W += (size_t)kz * 44 * Kd;
    }
    float acc[4][4] = {};

    for (int k0 = 0; k0 < Kd; k0 += 32) {
        #pragma unroll
        for (int p = 0; p < 2; ++p) {
            int r = (tid >> 3) + p * 32;
            int kv = (tid & 7) * 4;
            int m = m0 + r;
            float4 v;
            if constexpr (MODE == 3) {
                int b = m / LPIX, l = m % LPIX;
                const float* px = Ause + ((size_t)(b * 96 + k0 + kv)) * LPIX + l;
                v.x = px[0]; v.y = px[LPIX]; v.z = px[2 * LPIX]; v.w = px[3 * LPIX];
            } else {
                v = *reinterpret_cast<const float4*>(Ause + (size_t)m * Kd + k0 + kv);
                if constexpr (MODE == 2) {
                    float4 r2 = *reinterpret_cast<const float4*>(A2 + (size_t)m * Kd + k0 + kv);
                    v.x += r2.x; v.y += r2.y; v.z += r2.z; v.w += r2.w;
                }
            }
            As[kv + 0][r] = v.x; As[kv + 1][r] = v.y;
            As[kv + 2][r] = v.z; As[kv + 3][r] = v.w;
        }
        #pragma unroll
        for (int p = 0; p < 2; ++p) {
            int r = (tid >> 3) + p * 32;
            int kv = (tid & 7) * 4;
            int n = n0 + r;
            float4 v = make_float4(0.f, 0.f, 0.f, 0.f);
            if (n < N) v = *reinterpret_cast<const float4*>(W + (size_t)n * Kd + k0 + kv);
            Ws[kv + 0][r] = v.x; Ws[kv + 1][r] = v.y;
            Ws[kv + 2][r] = v.z; Ws[kv + 3][r] = v.w;
        }
        __syncthreads();
        #pragma unroll
        for (int kk = 0; kk < 32; ++kk) {
            float4 a = *reinterpret_cast<const float4*>(&As[kk][mi * 4]);
            float4 b = *reinterpret_cast<const float4*>(&Ws[kk][ni * 4]);
            float av[4] = {a.x, a.y, a.z, a.w};
            float bv[4] = {b.x, b.y, b.z, b.w};
            #pragma unroll
            for (int i = 0; i < 4; ++i)
                #pragma unroll
                for (int j = 0; j < 4; ++j)
                    acc[i][j] = fmaf(av[i], bv[j], acc[i][j]);
        }
        __syncthreads();
    }

    #pragma unroll
    for (int i = 0; i < 4; ++i) {
        int m = m0 + mi * 4 + i;
        int b = m / LPIX, l = m % LPIX;
        #pragma unroll
        for (int j = 0; j < 4; ++j) {
            int o = n0 + ni * 4 + j;
            float v = acc[i][j];
            if constexpr (MODE == 0) {
                if (o < 384) out0[((size_t)(b * 384 + o)) * LPIX + l] = v;
                else         out1[(size_t)m * 384 + (o - 384)] = v;
            } else if constexpr (MODE == 1) {
                out0[(size_t)m * N + o] = v;
            } else if constexpr (MODE == 2) {
                if (o < N) out0[((size_t)(b * 96 + o)) * LPIX + l] = gelu_f(v + bias[o]);
            } else if constexpr (MODE == 3) {
                out0[(size_t)m * N + o] = gelu_f(v + bias[o]);
            } else { // MODE 4
                if (o < 44)
                    out0[(((size_t)b * 4 + kz) * LPIX + l) * 44 + o] = v;
            }
        }
    }
}

// ---------------- depthwise 3x3 SAME + bias + SiLU --------------------------
__global__ __launch_bounds__(256) void dwconv_k(
    const float* __restrict__ xin, const float* __restrict__ w9,
    const float* __restrict__ bias, float* __restrict__ xout)
{
    int f = blockIdx.x * 256 + threadIdx.x;
    if (f >= LPIX) return;
    int c = blockIdx.y, b = blockIdx.z;
    const float* p = xin + ((size_t)b * 384 + c) * LPIX;
    int h = f / HH, w = f % HH;
    float s = bias[c];
    #pragma unroll
    for (int dh = -1; dh <= 1; ++dh) {
        int h2 = h + dh;
        if ((unsigned)h2 >= HH) continue;
        #pragma unroll
        for (int dw = -1; dw <= 1; ++dw) {
            int w2 = w + dw;
            if ((unsigned)w2 >= HH) continue;
            s = fmaf(p[h2 * HH + w2], w9[c * 9 + (dh + 1) * 3 + (dw + 1)], s);
        }
    }
    xout[((size_t)b * 384 + c) * LPIX + f] = s / (1.f + __expf(-s));
}

// ---------------- transpose raster: xi planar -> xiR (b,t,384) + y0 init ----
__global__ __launch_bounds__(256) void transR_k(
    const float* __restrict__ xi, const float* __restrict__ Ds,
    float* __restrict__ xiR, float* __restrict__ y0)
{
    __shared__ float T[64][65];
    int f0 = blockIdx.x * 64, d0 = blockIdx.y * 64, b = blockIdx.z;
    int tid = threadIdx.x;
    #pragma unroll
    for (int i = 0; i < 16; ++i) {
        int idx = tid + i * 256;
        int dl = idx >> 6, fl = idx & 63;
        T[dl][fl] = xi[((size_t)b * 384 + d0 + dl) * LPIX + f0 + fl];
    }
    __syncthreads();
    #pragma unroll
    for (int i = 0; i < 16; ++i) {
        int idx = tid + i * 256;
        int fl = idx >> 6, dl = idx & 63;
        int d = d0 + dl;
        float v = T[dl][fl];
        float sD = Ds[d] + Ds[384 + d] + Ds[768 + d] + Ds[1152 + d];
        size_t o = ((size_t)b * LPIX + f0 + fl) * 384 + d;
        xiR[o] = v;
        y0[o] = v * sD;
    }
}

// ---------------- transpose spatial: xiT[b, w*56+h, d] = xi[b, d, h*56+w] ---
__global__ __launch_bounds__(256) void transT_k(
    const float* __restrict__ xi, float* __restrict__ xiT)
{
    __shared__ float T[64][57];
    int d0 = blockIdx.x * 64, h = blockIdx.y, b = blockIdx.z;
    int tid = threadIdx.x;
    #pragma unroll
    for (int i = 0; i < 14; ++i) {
        int idx = tid + i * 256;
        int dl = idx / 56, wl = idx % 56;
        T[dl][wl] = xi[((size_t)b * 384 + d0 + dl) * LPIX + h * 56 + wl];
    }
    __syncthreads();
    #pragma unroll
    for (int i = 0; i < 14; ++i) {
        int idx = tid + i * 256;
        int wl = idx >> 6, dl = idx & 63;
        xiT[((size_t)b * LPIX + wl * 56 + h) * 384 + d0 + dl] = T[dl][wl];
    }
}

// ---------------- dt GEMM: dT[b,k,t,384] = softplus(dtlow @ dtw^T + b) ------
__global__ __launch_bounds__(256) void dtgemm_k(
    const float* __restrict__ xdblT, const float* __restrict__ dtw,
    const float* __restrict__ dtb, float* __restrict__ dT)
{
    __shared__ float As[64][13];
    __shared__ float Ws[64][13];
    int t0 = blockIdx.x * 64, d0 = blockIdx.y * 64;
    int bk = blockIdx.z, k = bk & 3;
    int tid = threadIdx.x;
    const float* Ab = xdblT + ((size_t)bk * LPIX + t0) * 44;
    for (int i = tid; i < 768; i += 256) {
        int tt = i / 12, r = i % 12;
        As[tt][r] = Ab[(size_t)tt * 44 + r];
    }
    for (int i = tid; i < 768; i += 256) {
        int dd = i / 12, r = i % 12;
        Ws[dd][r] = dtw[((size_t)k * 384 + d0 + dd) * 12 + r];
    }
    __syncthreads();
    int mi = tid >> 4, ni = tid & 15;
    float acc[4][4] = {};
    #pragma unroll
    for (int r = 0; r < 12; ++r) {
        float av[4], bv[4];
        #pragma unroll
        for (int i = 0; i < 4; ++i) av[i] = As[mi * 4 + i][r];
        #pragma unroll
        for (int j = 0; j < 4; ++j) bv[j] = Ws[ni * 4 + j][r];
        #pragma unroll
        for (int i = 0; i < 4; ++i)
            #pragma unroll
            for (int j = 0; j < 4; ++j)
                acc[i][j] = fmaf(av[i], bv[j], acc[i][j]);
    }
    #pragma unroll
    for (int i = 0; i < 4; ++i) {
        int t = t0 + mi * 4 + i;
        #pragma unroll
        for (int j = 0; j < 4; ++j) {
            int d = d0 + ni * 4 + j;
            float s = acc[i][j] + dtb[k * 384 + d];
            s = (s > 20.f) ? s : log1pf(__expf(s));
            dT[((size_t)bk * LPIX + t) * 384 + d] = s;
        }
    }
}

// ---------------- scan phase 1: per-segment local scan (h, P) --------------
__global__ __launch_bounds__(256) void scan1_k(
    const float* __restrict__ dT, const float* __restrict__ xiR,
    const float* __restrict__ xiT, const float* __restrict__ xdblT,
    const float* __restrict__ A_log, float* __restrict__ lh,
    float* __restrict__ Pb)
{
    int w = blockIdx.x * 4 + (threadIdx.x >> 6);     // 0..12287
    int lane = threadIdx.x & 63;
    int g = lane >> 4, n = lane & 15;
    int seg = w & (SEG - 1);
    int dblk = (w >> 4) % 96;
    int bk = w / (SEG * 96);
    int b = bk >> 2, k = bk & 3;
    int d = dblk * 4 + g;
    int kk = k & 1, rev = k >> 1;

    float Aneg = -__expf(A_log[((size_t)k * 384 + d) * 16 + n]);
    const float* pd = dT + (size_t)bk * LPIX * 384 + d;
    const float* pu = (kk ? xiT : xiR) + (size_t)b * LPIX * 384 + d;
    const float* pbc = xdblT + (size_t)bk * LPIX * 44;

    int t0 = seg * SEGLEN;
    int fpos = rev ? (LPIX - 1 - t0) : t0;
    int dir = rev ? -1 : 1;
    float h = 0.f, P = 1.f;
    #pragma unroll 2
    for (int s = 0; s < SEGLEN; ++s) {
        float dl = pd[(size_t)fpos * 384];
        float u  = pu[(size_t)fpos * 384];
        float Bv = pbc[fpos * 44 + 12 + n];
        float a = __expf(dl * Aneg);
        h = fmaf(a, h, dl * u * Bv);
        P *= a;
        fpos += dir;
    }
    size_t base = (((size_t)seg * 8 + bk) * 384 + d) * 16 + n;
    lh[base] = h;
    Pb[base] = P;
}

// ---------------- scan phase 2: sequential combine over segments -----------
__global__ __launch_bounds__(256) void scan2_k(
    float* __restrict__ lh, const float* __restrict__ Pb)
{
    int w = blockIdx.x * 4 + (threadIdx.x >> 6);     // 0..767
    int lane = threadIdx.x & 63;
    int g = lane >> 4, n = lane & 15;
    int dblk = w % 96, bk = w / 96;
    int d = dblk * 4 + g;
    float h = 0.f;
    for (int s = 0; s < SEG; ++s) {
        size_t base = (((size_t)s * 8 + bk) * 384 + d) * 16 + n;
        float lhv = lh[base], Pv = Pb[base];
        lh[base] = h;                 // h_in for this segment
        h = fmaf(Pv, h, lhv);
    }
}

// ---------------- scan phase 3: full scan from h_in, y atomics -------------
__global__ __launch_bounds__(256) void scan3_k(
    const float* __restrict__ dT, const float* __restrict__ xiR,
    const float* __restrict__ xiT, const float* __restrict__ xdblT,
    const float* __restrict__ A_log, const float* __restrict__ lh,
    float* __restrict__ y0)
{
    int w = blockIdx.x * 4 + (threadIdx.x >> 6);
    int lane = threadIdx.x & 63;
    int g = lane >> 4, n = lane & 15;
    int seg = w & (SEG - 1);
    int dblk = (w >> 4) % 96;
    int bk = w / (SEG * 96);
    int b = bk >> 2, k = bk & 3;
    int d = dblk * 4 + g;
    int kk = k & 1, rev = k >> 1;

    float Aneg = -__expf(A_log[((size_t)k * 384 + d) * 16 + n]);
    const float* pd = dT + (size_t)bk * LPIX * 384 + d;
    const float* pu = (kk ? xiT : xiR) + (size_t)b * LPIX * 384 + d;
    const float* pbc = xdblT + (size_t)bk * LPIX * 44;
    float* py = y0 + (size_t)b * LPIX * 384 + d;

    int t0 = seg * SEGLEN;
    int fpos = rev ? (LPIX - 1 - t0) : t0;
    int dir = rev ? -1 : 1;
    int r = 0, q = 0;
    if (kk) { r = fpos % 56; q = fpos / 56; }

    float h = lh[(((size_t)seg * 8 + bk) * 384 + d) * 16 + n];

    #pragma unroll 2
    for (int s = 0; s < SEGLEN; ++s) {
        float dl = pd[(size_t)fpos * 384];
        float u  = pu[(size_t)fpos * 384];
        float Bv = pbc[fpos * 44 + 12 + n];
        float Cv = pbc[fpos * 44 + 28 + n];
        float a = __expf(dl * Aneg);
        h = fmaf(a, h, dl * u * Bv);
        float p = dpp_shr_sum16(h * Cv);
        int f = kk ? (r * 56 + q) : fpos;
        if (n == 15)
            __hip_atomic_fetch_add(py + (size_t)f * 384, p,
                                   __ATOMIC_RELAXED, __HIP_MEMORY_SCOPE_AGENT);
        fpos += dir;
        if (kk) {
            r += dir;
            if (r == 56) { r = 0; ++q; }
            if (r < 0)   { r = 55; --q; }
        }
    }
}

// ---------------- LayerNorm + SiLU gate -------------------------------------
__global__ __launch_bounds__(256) void lngate_k(
    const float* __restrict__ y0, const float* __restrict__ z,
    const float* __restrict__ lng, const float* __restrict__ lnb,
    float* __restrict__ gbuf)
{
    int m = blockIdx.x * 4 + (threadIdx.x >> 6);
    int lane = threadIdx.x & 63;
    const float* py = y0 + (size_t)m * 384;
    float v[6];
    float s = 0.f, sq = 0.f;
    #pragma unroll
    for (int i = 0; i < 6; ++i) {
        v[i] = py[lane + i * 64];
        s += v[i]; sq += v[i] * v[i];
    }
    #pragma unroll
    for (int off = 1; off < 64; off <<= 1) {
        s += __shfl_xor(s, off);
        sq += __shfl_xor(sq, off);
    }
    float mu = s * (1.f / 384.f);
    float var = sq * (1.f / 384.f) - mu * mu;
    float rs = rsqrtf(var + 1e-5f);
    const float* pz = z + (size_t)m * 384;
    float* pg = gbuf + (size_t)m * 384;
    #pragma unroll
    for (int i = 0; i < 6; ++i) {
        int c = lane + i * 64;
        float nv = (v[i] - mu) * rs * lng[c] + lnb[c];
        float zv = pz[c];
        pg[c] = nv * (zv / (1.f + __expf(-zv)));
    }
}

// ---------------- host side -------------------------------------------------
extern "C" void kernel_launch(void* const* d_in, const int* in_sizes, int n_in,
                              void* d_out, int out_size, void* d_ws, size_t ws_size,
                              hipStream_t stream) {
    const float* x        = (const float*)d_in[0];
    const float* w_init   = (const float*)d_in[1];
    const float* b_init   = (const float*)d_in[2];
    const float* w_inproj = (const float*)d_in[3];
    const float* w_conv   = (const float*)d_in[4];
    const float* b_conv   = (const float*)d_in[5];
    const float* w_xproj  = (const float*)d_in[6];
    const float* w_dt     = (const float*)d_in[7];
    const float* b_dt     = (const float*)d_in[8];
    const float* A_log    = (const float*)d_in[9];
    const float* Ds       = (const float*)d_in[10];
    const float* ln_g     = (const float*)d_in[11];
    const float* ln_b     = (const float*)d_in[12];
    const float* w_out    = (const float*)d_in[13];
    const float* w_fina   = (const float*)d_in[14];
    const float* b_fina   = (const float*)d_in[15];

    float* ws    = (float*)d_ws;
    float* x1    = ws + 0;
    float* z     = ws + 1204224;
    float* xiR   = ws + 3612672;    // later reused as gbuf
    float* xiT   = ws + 6021120;
    float* xdblT = ws + 8429568;
    float* dT    = ws + 9533440;    // later reused as y2
    float* xiraw = ws + 9533440;    // transient (dies before dT written)
    float* xi    = ws + 11941888;   // transient (dies before dT written)
    float* y0    = ws + 19167232;
    float* lh    = ws + 21575680;
    float* Pb    = ws + 22362112;
    float* out   = (float*)d_out;

    // 1) x1 = gelu(conv_init(x))                 (B,L,192)
    gemm_k<3><<<dim3(98, 3), 256, 0, stream>>>(x, nullptr, w_init, b_init,
                                               x1, nullptr, 6272, 192, 96);
    // 2) in_proj -> xiraw planar + z
    gemm_k<0><<<dim3(98, 12), 256, 0, stream>>>(x1, nullptr, w_inproj, nullptr,
                                                xiraw, z, 6272, 768, 192);
    // 3) depthwise 3x3 + SiLU -> xi planar
    dwconv_k<<<dim3(13, 384, 2), 256, 0, stream>>>(xiraw, w_conv, b_conv, xi);
    // 4) transposes: xi -> xiR (+ y0 = xi*sumD), xi -> xiT
    transR_k<<<dim3(49, 6, 2), 256, 0, stream>>>(xi, Ds, xiR, y0);
    transT_k<<<dim3(6, 56, 2), 256, 0, stream>>>(xi, xiT);
    // 5) x_proj GEMM -> xdblT[b,k,t,44]  (xi now dead)
    gemm_k<4><<<dim3(98, 1, 4), 256, 0, stream>>>(xiR, xiT, w_xproj, nullptr,
                                                  xdblT, nullptr, 6272, 44, 384);
    // 6) dt GEMM + softplus -> dT[b,k,t,384]  (overwrites xiraw/xi region)
    dtgemm_k<<<dim3(49, 6, 8), 256, 0, stream>>>(xdblT, w_dt, b_dt, dT);
    // 7) segmented scan
    scan1_k<<<3072, 256, 0, stream>>>(dT, xiR, xiT, xdblT, A_log, lh, Pb);
    scan2_k<<<192, 256, 0, stream>>>(lh, Pb);
    scan3_k<<<3072, 256, 0, stream>>>(dT, xiR, xiT, xdblT, A_log, lh, y0);
    // 8) LayerNorm + SiLU(z) gate -> gbuf (reuses xiR)
    lngate_k<<<1568, 256, 0, stream>>>(y0, z, ln_g, ln_b, xiR);
    // 9) out_proj -> y2 (reuses dT)
    gemm_k<1><<<dim3(98, 3), 256, 0, stream>>>(xiR, nullptr, w_out, nullptr,
                                               dT, nullptr, 6272, 192, 384);
    // 10) final: gelu(conv_fina(y2 + x1)) -> out planar (B,96,56,56)
    gemm_k<2><<<dim3(98, 2), 256, 0, stream>>>(dT, x1, w_fina, b_fina,
                                               out, nullptr, 6272, 96, 192);
}

// Round 3
// 399.658 us; speedup vs baseline: 2.3640x; 1.4229x over previous
//
#include <hip/hip_runtime.h>

// SS2D / VMamba block, fp32. Round 3: scan remapped to 4 states/lane
// (lane = 16 d x 4 n-quad, h[4] in registers), SEG=32, exp2-folded A,
// quad-perm DPP reduce, stride-48 xdbl rows for aligned float4 B/C loads.
//
// B=2, H=W=56, L=3136, D_MODEL=192, D_INNER=384, N=16, K=4, DT_RANK=12.
//
// Workspace layout (float offsets):
//   x1    @ 0         (B,L,192)    1,204,224
//   z     @ 1204224   (B,L,384)    2,408,448
//   xiR   @ 3612672   (B,L,384)    2,408,448   raster t-major  -> gbuf later
//   xiT   @ 6021120   (B,L,384)    2,408,448   transposed t-major
//   xdblT @ 8429568   (B,4,L,48)   1,204,224   dt 0-11, B 12-27, C 28-43, pad
//   dT    @ 9633792   (B,4,L,384)  9,633,792   delta scan order -> y2 later
//     (xiraw planar @9633792, xi planar @12042240 live transiently here)
//   y0    @ 19267584  (B,L,384)    2,408,448
//   lh    @ 21676032  (32,8,384,16) 1,572,864
//   sumd  @ 23248896  (32,8,384)      98,304
// total 23,347,200 floats = 93.4 MB

#define LPIX 3136
#define HH 56
#define SEG 32
#define SEGLEN 98

__device__ __forceinline__ float gelu_f(float x) {
    return 0.5f * x * (1.0f + erff(x * 0.70710678118654752f));
}

__device__ __forceinline__ float quad_sum(float p) {
    // sum across the 4 lanes of each quad (all lanes end with the total)
    p += __int_as_float(__builtin_amdgcn_update_dpp(0, __float_as_int(p), 0xB1, 0xf, 0xf, true));
    p += __int_as_float(__builtin_amdgcn_update_dpp(0, __float_as_int(p), 0x4E, 0xf, 0xf, true));
    return p;
}

// ---------------- shared fp32 GEMM: C = A * W^T (tiles 64x64, BK=32) --------
// MODE 0: o<384 -> out0 planar (B,384,L); o>=384 -> out1 (M,384) [z]
// MODE 1: out0 row-major (M,N)
// MODE 2: A_eff = A + A2; gelu(v+bias) -> planar (B,96,L) [final out]
// MODE 3: A planar (B,96,L); gelu(v+bias) -> row-major (M,N) [x1]
// MODE 4: x_proj: A=(xiR), A2=(xiT) picked by blockIdx.z&1; W=xpw[k];
//         out xdblT[b,k,t,48] (N=44 masked, rows padded to 48)
template <int MODE>
__global__ __launch_bounds__(256) void gemm_k(
    const float* __restrict__ A, const float* __restrict__ A2,
    const float* __restrict__ W, const float* __restrict__ bias,
    float* __restrict__ out0, float* __restrict__ out1,
    int M, int N, int Kd)
{
    __shared__ __align__(16) float As[32][68];
    __shared__ __align__(16) float Ws[32][68];
    const int tid = threadIdx.x;
    const int m0 = blockIdx.x * 64;
    const int n0 = blockIdx.y * 64;
    const int kz = blockIdx.z;
    const int mi = tid >> 4, ni = tid & 15;
    const float* Ause = A;
    if constexpr (MODE == 4) {
        if (kz & 1) Ause = A2;
        W += (size_t)kz * 44 * Kd;
    }
    float acc[4][4] = {};

    for (int k0 = 0; k0 < Kd; k0 += 32) {
        #pragma unroll
        for (int p = 0; p < 2; ++p) {
            int r = (tid >> 3) + p * 32;
            int kv = (tid & 7) * 4;
            int m = m0 + r;
            float4 v;
            if constexpr (MODE == 3) {
                int b = m / LPIX, l = m % LPIX;
                const float* px = Ause + ((size_t)(b * 96 + k0 + kv)) * LPIX + l;
                v.x = px[0]; v.y = px[LPIX]; v.z = px[2 * LPIX]; v.w = px[3 * LPIX];
            } else {
                v = *reinterpret_cast<const float4*>(Ause + (size_t)m * Kd + k0 + kv);
                if constexpr (MODE == 2) {
                    float4 r2 = *reinterpret_cast<const float4*>(A2 + (size_t)m * Kd + k0 + kv);
                    v.x += r2.x; v.y += r2.y; v.z += r2.z; v.w += r2.w;
                }
            }
            As[kv + 0][r] = v.x; As[kv + 1][r] = v.y;
            As[kv + 2][r] = v.z; As[kv + 3][r] = v.w;
        }
        #pragma unroll
        for (int p = 0; p < 2; ++p) {
            int r = (tid >> 3) + p * 32;
            int kv = (tid & 7) * 4;
            int n = n0 + r;
            float4 v = make_float4(0.f, 0.f, 0.f, 0.f);
            if (n < N) v = *reinterpret_cast<const float4*>(W + (size_t)n * Kd + k0 + kv);
            Ws[kv + 0][r] = v.x; Ws[kv + 1][r] = v.y;
            Ws[kv + 2][r] = v.z; Ws[kv + 3][r] = v.w;
        }
        __syncthreads();
        #pragma unroll
        for (int kk = 0; kk < 32; ++kk) {
            float4 a = *reinterpret_cast<const float4*>(&As[kk][mi * 4]);
            float4 b = *reinterpret_cast<const float4*>(&Ws[kk][ni * 4]);
            float av[4] = {a.x, a.y, a.z, a.w};
            float bv[4] = {b.x, b.y, b.z, b.w};
            #pragma unroll
            for (int i = 0; i < 4; ++i)
                #pragma unroll
                for (int j = 0; j < 4; ++j)
                    acc[i][j] = fmaf(av[i], bv[j], acc[i][j]);
        }
        __syncthreads();
    }

    #pragma unroll
    for (int i = 0; i < 4; ++i) {
        int m = m0 + mi * 4 + i;
        int b = m / LPIX, l = m % LPIX;
        #pragma unroll
        for (int j = 0; j < 4; ++j) {
            int o = n0 + ni * 4 + j;
            float v = acc[i][j];
            if constexpr (MODE == 0) {
                if (o < 384) out0[((size_t)(b * 384 + o)) * LPIX + l] = v;
                else         out1[(size_t)m * 384 + (o - 384)] = v;
            } else if constexpr (MODE == 1) {
                out0[(size_t)m * N + o] = v;
            } else if constexpr (MODE == 2) {
                if (o < N) out0[((size_t)(b * 96 + o)) * LPIX + l] = gelu_f(v + bias[o]);
            } else if constexpr (MODE == 3) {
                out0[(size_t)m * N + o] = gelu_f(v + bias[o]);
            } else { // MODE 4
                if (o < 44)
                    out0[(((size_t)b * 4 + kz) * LPIX + l) * 48 + o] = v;
            }
        }
    }
}

// ---------------- depthwise 3x3 SAME + bias + SiLU --------------------------
__global__ __launch_bounds__(256) void dwconv_k(
    const float* __restrict__ xin, const float* __restrict__ w9,
    const float* __restrict__ bias, float* __restrict__ xout)
{
    int f = blockIdx.x * 256 + threadIdx.x;
    if (f >= LPIX) return;
    int c = blockIdx.y, b = blockIdx.z;
    const float* p = xin + ((size_t)b * 384 + c) * LPIX;
    int h = f / HH, w = f % HH;
    float s = bias[c];
    #pragma unroll
    for (int dh = -1; dh <= 1; ++dh) {
        int h2 = h + dh;
        if ((unsigned)h2 >= HH) continue;
        #pragma unroll
        for (int dw = -1; dw <= 1; ++dw) {
            int w2 = w + dw;
            if ((unsigned)w2 >= HH) continue;
            s = fmaf(p[h2 * HH + w2], w9[c * 9 + (dh + 1) * 3 + (dw + 1)], s);
        }
    }
    xout[((size_t)b * 384 + c) * LPIX + f] = s / (1.f + __expf(-s));
}

// ---------------- transpose raster: xi planar -> xiR (b,t,384) + y0 init ----
__global__ __launch_bounds__(256) void transR_k(
    const float* __restrict__ xi, const float* __restrict__ Ds,
    float* __restrict__ xiR, float* __restrict__ y0)
{
    __shared__ float T[64][65];
    int f0 = blockIdx.x * 64, d0 = blockIdx.y * 64, b = blockIdx.z;
    int tid = threadIdx.x;
    #pragma unroll
    for (int i = 0; i < 16; ++i) {
        int idx = tid + i * 256;
        int dl = idx >> 6, fl = idx & 63;
        T[dl][fl] = xi[((size_t)b * 384 + d0 + dl) * LPIX + f0 + fl];
    }
    __syncthreads();
    #pragma unroll
    for (int i = 0; i < 16; ++i) {
        int idx = tid + i * 256;
        int fl = idx >> 6, dl = idx & 63;
        int d = d0 + dl;
        float v = T[dl][fl];
        float sD = Ds[d] + Ds[384 + d] + Ds[768 + d] + Ds[1152 + d];
        size_t o = ((size_t)b * LPIX + f0 + fl) * 384 + d;
        xiR[o] = v;
        y0[o] = v * sD;
    }
}

// ---------------- transpose spatial: xiT[b, w*56+h, d] = xi[b, d, h*56+w] ---
__global__ __launch_bounds__(256) void transT_k(
    const float* __restrict__ xi, float* __restrict__ xiT)
{
    __shared__ float T[64][57];
    int d0 = blockIdx.x * 64, h = blockIdx.y, b = blockIdx.z;
    int tid = threadIdx.x;
    #pragma unroll
    for (int i = 0; i < 14; ++i) {
        int idx = tid + i * 256;
        int dl = idx / 56, wl = idx % 56;
        T[dl][wl] = xi[((size_t)b * 384 + d0 + dl) * LPIX + h * 56 + wl];
    }
    __syncthreads();
    #pragma unroll
    for (int i = 0; i < 14; ++i) {
        int idx = tid + i * 256;
        int wl = idx >> 6, dl = idx & 63;
        xiT[((size_t)b * LPIX + wl * 56 + h) * 384 + d0 + dl] = T[dl][wl];
    }
}

// ---------------- dt GEMM: dT[b,k,t,384] = softplus(dtlow @ dtw^T + b) ------
__global__ __launch_bounds__(256) void dtgemm_k(
    const float* __restrict__ xdblT, const float* __restrict__ dtw,
    const float* __restrict__ dtb, float* __restrict__ dT)
{
    __shared__ float As[64][13];
    __shared__ float Ws[64][13];
    int t0 = blockIdx.x * 64, d0 = blockIdx.y * 64;
    int bk = blockIdx.z, k = bk & 3;
    int tid = threadIdx.x;
    const float* Ab = xdblT + ((size_t)bk * LPIX + t0) * 48;
    for (int i = tid; i < 768; i += 256) {
        int tt = i / 12, r = i % 12;
        As[tt][r] = Ab[(size_t)tt * 48 + r];
    }
    for (int i = tid; i < 768; i += 256) {
        int dd = i / 12, r = i % 12;
        Ws[dd][r] = dtw[((size_t)k * 384 + d0 + dd) * 12 + r];
    }
    __syncthreads();
    int mi = tid >> 4, ni = tid & 15;
    float acc[4][4] = {};
    #pragma unroll
    for (int r = 0; r < 12; ++r) {
        float av[4], bv[4];
        #pragma unroll
        for (int i = 0; i < 4; ++i) av[i] = As[mi * 4 + i][r];
        #pragma unroll
        for (int j = 0; j < 4; ++j) bv[j] = Ws[ni * 4 + j][r];
        #pragma unroll
        for (int i = 0; i < 4; ++i)
            #pragma unroll
            for (int j = 0; j < 4; ++j)
                acc[i][j] = fmaf(av[i], bv[j], acc[i][j]);
    }
    #pragma unroll
    for (int i = 0; i < 4; ++i) {
        int t = t0 + mi * 4 + i;
        #pragma unroll
        for (int j = 0; j < 4; ++j) {
            int d = d0 + ni * 4 + j;
            float s = acc[i][j] + dtb[k * 384 + d];
            s = (s > 20.f) ? s : log1pf(__expf(s));
            dT[((size_t)bk * LPIX + t) * 384 + d] = s;
        }
    }
}

// ---------------- scan phase 1: local scan, h[4]/lane; store lh + sum(dl) ---
// wave: 16 d x (4 n per lane quad). lane = dl*4 + nq.
__global__ __launch_bounds__(256) void scan1_k(
    const float* __restrict__ dT, const float* __restrict__ xiR,
    const float* __restrict__ xiT, const float* __restrict__ xdblT,
    const float* __restrict__ A_log, float* __restrict__ lh,
    float* __restrict__ sumd)
{
    int w = blockIdx.x * 4 + (threadIdx.x >> 6);       // 0..6143
    int lane = threadIdx.x & 63;
    int dl_ = lane >> 2, nq = lane & 3;
    int seg = w & (SEG - 1);
    int dblk = (w >> 5) % 24;
    int bk = w / (SEG * 24);
    int b = bk >> 2, k = bk & 3;
    int d = dblk * 16 + dl_;

    float4 Ar = *reinterpret_cast<const float4*>(A_log + ((size_t)(k * 384 + d)) * 16 + nq * 4);
    float A2[4] = { -__expf(Ar.x) * 1.44269504f, -__expf(Ar.y) * 1.44269504f,
                    -__expf(Ar.z) * 1.44269504f, -__expf(Ar.w) * 1.44269504f };

    const float* pD = dT + (size_t)bk * LPIX * 384;
    const float* pU = ((k & 1) ? xiT : xiR) + (size_t)b * LPIX * 384;
    const float* pBC = xdblT + (size_t)bk * LPIX * 48;

    int t0 = seg * SEGLEN;
    int rev = k >> 1;
    int fpos0 = rev ? (LPIX - 1 - t0) : t0;
    int stepd = rev ? -384 : 384;
    int stepbc = rev ? -48 : 48;

    unsigned idx = (unsigned)fpos0 * 384u + (unsigned)d;
    unsigned ibc = (unsigned)fpos0 * 48u + 12u + (unsigned)nq * 4u;

    float h0 = 0.f, h1 = 0.f, h2 = 0.f, h3 = 0.f, sd = 0.f;

    float dlv = pD[idx], uv = pU[idx];
    float4 Bv = *reinterpret_cast<const float4*>(pBC + ibc);
    for (int s = 0; s < SEGLEN; ++s) {
        float dln, un; float4 Bn;
        if (s < SEGLEN - 1) {
            idx += stepd; ibc += stepbc;
            dln = pD[idx]; un = pU[idx];
            Bn = *reinterpret_cast<const float4*>(pBC + ibc);
        }
        sd += dlv;
        float dlu = dlv * uv;
        h0 = fmaf(__builtin_amdgcn_exp2f(dlv * A2[0]), h0, dlu * Bv.x);
        h1 = fmaf(__builtin_amdgcn_exp2f(dlv * A2[1]), h1, dlu * Bv.y);
        h2 = fmaf(__builtin_amdgcn_exp2f(dlv * A2[2]), h2, dlu * Bv.z);
        h3 = fmaf(__builtin_amdgcn_exp2f(dlv * A2[3]), h3, dlu * Bv.w);
        dlv = dln; uv = un; Bv = Bn;
    }
    size_t hb = (((size_t)seg * 8 + bk) * 384 + d) * 16 + nq * 4;
    *reinterpret_cast<float4*>(lh + hb) = make_float4(h0, h1, h2, h3);
    if (nq == 0)
        sumd[((size_t)seg * 8 + bk) * 384 + d] = sd;
}

// ---------------- scan phase 2: sequential combine over segments -----------
__global__ __launch_bounds__(256) void scan2_k(
    float* __restrict__ lh, const float* __restrict__ sumd,
    const float* __restrict__ A_log)
{
    int idx = blockIdx.x * 256 + threadIdx.x;          // 0..49151
    int n = idx & 15;
    int d = (idx >> 4) % 384;
    int bk = idx / (384 * 16);
    int k = bk & 3;
    float A2 = -__expf(A_log[((size_t)(k * 384 + d)) * 16 + n]) * 1.44269504f;
    float h = 0.f;
    for (int s = 0; s < SEG; ++s) {
        size_t base = (((size_t)s * 8 + bk) * 384 + d) * 16 + n;
        float lhv = lh[base];
        float P = __builtin_amdgcn_exp2f(sumd[((size_t)s * 8 + bk) * 384 + d] * A2);
        lh[base] = h;                 // h_in for this segment
        h = fmaf(P, h, lhv);
    }
}

// ---------------- scan phase 3: full scan from h_in, coalesced atomics -----
template <int KK, int REV>
__device__ __forceinline__ void scan3_body(
    int b, int bk, int k, int seg, int d, int nq, int lane,
    const float* __restrict__ dT, const float* __restrict__ pU,
    const float* __restrict__ xdblT, const float* __restrict__ A_log,
    const float* __restrict__ lh, float* __restrict__ y0)
{
    float4 Ar = *reinterpret_cast<const float4*>(A_log + ((size_t)(k * 384 + d)) * 16 + nq * 4);
    float A2[4] = { -__expf(Ar.x) * 1.44269504f, -__expf(Ar.y) * 1.44269504f,
                    -__expf(Ar.z) * 1.44269504f, -__expf(Ar.w) * 1.44269504f };

    const float* pD = dT + (size_t)bk * LPIX * 384;
    const float* pBC = xdblT + (size_t)bk * LPIX * 48;
    float* pY = y0 + (size_t)b * LPIX * 384;

    int t0 = seg * SEGLEN;
    int fpos0 = REV ? (LPIX - 1 - t0) : t0;
    constexpr int stepd = REV ? -384 : 384;
    constexpr int stepbc = REV ? -48 : 48;

    unsigned idx = (unsigned)fpos0 * 384u + (unsigned)d;
    unsigned ibc = (unsigned)fpos0 * 48u + 12u + (unsigned)nq * 4u;

    unsigned iy; int rr;
    if constexpr (KK) {
        int r0 = fpos0 % 56, q0 = fpos0 / 56;
        rr = r0;
        iy = (unsigned)(r0 * 56 + q0) * 384u + (unsigned)d;
    } else {
        iy = idx;
        rr = 0; (void)rr;
    }

    size_t hb = (((size_t)seg * 8 + bk) * 384 + d) * 16 + nq * 4;
    float4 h4 = *reinterpret_cast<const float4*>(lh + hb);
    float h0 = h4.x, h1 = h4.y, h2 = h4.z, h3 = h4.w;

    float dlv = pD[idx], uv = pU[idx];
    float4 Bv = *reinterpret_cast<const float4*>(pBC + ibc);
    float4 Cv = *reinterpret_cast<const float4*>(pBC + ibc + 16);

    for (int s = 0; s < SEGLEN; ++s) {
        float dln, un; float4 Bn, Cn;
        if (s < SEGLEN - 1) {
            idx += stepd; ibc += stepbc;
            dln = pD[idx]; un = pU[idx];
            Bn = *reinterpret_cast<const float4*>(pBC + ibc);
            Cn = *reinterpret_cast<const float4*>(pBC + ibc + 16);
        }
        float dlu = dlv * uv;
        h0 = fmaf(__builtin_amdgcn_exp2f(dlv * A2[0]), h0, dlu * Bv.x);
        float p = h0 * Cv.x;
        h1 = fmaf(__builtin_amdgcn_exp2f(dlv * A2[1]), h1, dlu * Bv.y);
        p = fmaf(h1, Cv.y, p);
        h2 = fmaf(__builtin_amdgcn_exp2f(dlv * A2[2]), h2, dlu * Bv.z);
        p = fmaf(h2, Cv.z, p);
        h3 = fmaf(__builtin_amdgcn_exp2f(dlv * A2[3]), h3, dlu * Bv.w);
        p = fmaf(h3, Cv.w, p);
        p = quad_sum(p);
        if ((lane & 3) == 0)
            __hip_atomic_fetch_add(pY + iy, p,
                                   __ATOMIC_RELAXED, __HIP_MEMORY_SCOPE_AGENT);
        if constexpr (KK) {
            if constexpr (REV) {
                bool wrap = (rr == 0);
                iy += wrap ? (unsigned)(3079 * 384) : (unsigned)(-56 * 384);
                rr = wrap ? 55 : rr - 1;
            } else {
                bool wrap = (rr == 55);
                iy += wrap ? (unsigned)(-3079 * 384) : (unsigned)(56 * 384);
                rr = wrap ? 0 : rr + 1;
            }
        } else {
            iy += (unsigned)stepd;
        }
        dlv = dln; uv = un; Bv = Bn; Cv = Cn;
    }
}

__global__ __launch_bounds__(256) void scan3_k(
    const float* __restrict__ dT, const float* __restrict__ xiR,
    const float* __restrict__ xiT, const float* __restrict__ xdblT,
    const float* __restrict__ A_log, const float* __restrict__ lh,
    float* __restrict__ y0)
{
    int w = blockIdx.x * 4 + (threadIdx.x >> 6);
    int lane = threadIdx.x & 63;
    int dl_ = lane >> 2, nq = lane & 3;
    int seg = w & (SEG - 1);
    int dblk = (w >> 5) % 24;
    int bk = w / (SEG * 24);
    int b = bk >> 2, k = bk & 3;
    int d = dblk * 16 + dl_;
    const float* pU = ((k & 1) ? xiT : xiR) + (size_t)b * LPIX * 384;
    if (k == 0)      scan3_body<0, 0>(b, bk, k, seg, d, nq, lane, dT, pU, xdblT, A_log, lh, y0);
    else if (k == 1) scan3_body<1, 0>(b, bk, k, seg, d, nq, lane, dT, pU, xdblT, A_log, lh, y0);
    else if (k == 2) scan3_body<0, 1>(b, bk, k, seg, d, nq, lane, dT, pU, xdblT, A_log, lh, y0);
    else             scan3_body<1, 1>(b, bk, k, seg, d, nq, lane, dT, pU, xdblT, A_log, lh, y0);
}

// ---------------- LayerNorm + SiLU gate -------------------------------------
__global__ __launch_bounds__(256) void lngate_k(
    const float* __restrict__ y0, const float* __restrict__ z,
    const float* __restrict__ lng, const float* __restrict__ lnb,
    float* __restrict__ gbuf)
{
    int m = blockIdx.x * 4 + (threadIdx.x >> 6);
    int lane = threadIdx.x & 63;
    const float* py = y0 + (size_t)m * 384;
    float v[6];
    float s = 0.f, sq = 0.f;
    #pragma unroll
    for (int i = 0; i < 6; ++i) {
        v[i] = py[lane + i * 64];
        s += v[i]; sq += v[i] * v[i];
    }
    #pragma unroll
    for (int off = 1; off < 64; off <<= 1) {
        s += __shfl_xor(s, off);
        sq += __shfl_xor(sq, off);
    }
    float mu = s * (1.f / 384.f);
    float var = sq * (1.f / 384.f) - mu * mu;
    float rs = rsqrtf(var + 1e-5f);
    const float* pz = z + (size_t)m * 384;
    float* pg = gbuf + (size_t)m * 384;
    #pragma unroll
    for (int i = 0; i < 6; ++i) {
        int c = lane + i * 64;
        float nv = (v[i] - mu) * rs * lng[c] + lnb[c];
        float zv = pz[c];
        pg[c] = nv * (zv / (1.f + __expf(-zv)));
    }
}

// ---------------- host side -------------------------------------------------
extern "C" void kernel_launch(void* const* d_in, const int* in_sizes, int n_in,
                              void* d_out, int out_size, void* d_ws, size_t ws_size,
                              hipStream_t stream) {
    const float* x        = (const float*)d_in[0];
    const float* w_init   = (const float*)d_in[1];
    const float* b_init   = (const float*)d_in[2];
    const float* w_inproj = (const float*)d_in[3];
    const float* w_conv   = (const float*)d_in[4];
    const float* b_conv   = (const float*)d_in[5];
    const float* w_xproj  = (const float*)d_in[6];
    const float* w_dt     = (const float*)d_in[7];
    const float* b_dt     = (const float*)d_in[8];
    const float* A_log    = (const float*)d_in[9];
    const float* Ds       = (const float*)d_in[10];
    const float* ln_g     = (const float*)d_in[11];
    const float* ln_b     = (const float*)d_in[12];
    const float* w_out    = (const float*)d_in[13];
    const float* w_fina   = (const float*)d_in[14];
    const float* b_fina   = (const float*)d_in[15];

    float* ws    = (float*)d_ws;
    float* x1    = ws + 0;
    float* z     = ws + 1204224;
    float* xiR   = ws + 3612672;    // later reused as gbuf
    float* xiT   = ws + 6021120;
    float* xdblT = ws + 8429568;
    float* dT    = ws + 9633792;    // later reused as y2
    float* xiraw = ws + 9633792;    // transient (dies before dT written)
    float* xi    = ws + 12042240;   // transient (dies before dT written)
    float* y0    = ws + 19267584;
    float* lh    = ws + 21676032;
    float* sumd  = ws + 23248896;
    float* out   = (float*)d_out;

    // 1) x1 = gelu(conv_init(x))                 (B,L,192)
    gemm_k<3><<<dim3(98, 3), 256, 0, stream>>>(x, nullptr, w_init, b_init,
                                               x1, nullptr, 6272, 192, 96);
    // 2) in_proj -> xiraw planar + z
    gemm_k<0><<<dim3(98, 12), 256, 0, stream>>>(x1, nullptr, w_inproj, nullptr,
                                                xiraw, z, 6272, 768, 192);
    // 3) depthwise 3x3 + SiLU -> xi planar
    dwconv_k<<<dim3(13, 384, 2), 256, 0, stream>>>(xiraw, w_conv, b_conv, xi);
    // 4) transposes: xi -> xiR (+ y0 = xi*sumD), xi -> xiT
    transR_k<<<dim3(49, 6, 2), 256, 0, stream>>>(xi, Ds, xiR, y0);
    transT_k<<<dim3(6, 56, 2), 256, 0, stream>>>(xi, xiT);
    // 5) x_proj GEMM -> xdblT[b,k,t,48]  (xi now dead)
    gemm_k<4><<<dim3(98, 1, 4), 256, 0, stream>>>(xiR, xiT, w_xproj, nullptr,
                                                  xdblT, nullptr, 6272, 44, 384);
    // 6) dt GEMM + softplus -> dT[b,k,t,384]  (overwrites xiraw/xi region)
    dtgemm_k<<<dim3(49, 6, 8), 256, 0, stream>>>(xdblT, w_dt, b_dt, dT);
    // 7) segmented scan (SEG=32)
    scan1_k<<<1536, 256, 0, stream>>>(dT, xiR, xiT, xdblT, A_log, lh, sumd);
    scan2_k<<<192, 256, 0, stream>>>(lh, sumd, A_log);
    scan3_k<<<1536, 256, 0, stream>>>(dT, xiR, xiT, xdblT, A_log, lh, y0);
    // 8) LayerNorm + SiLU(z) gate -> gbuf (reuses xiR)
    lngate_k<<<1568, 256, 0, stream>>>(y0, z, ln_g, ln_b, xiR);
    // 9) out_proj -> y2 (reuses dT)
    gemm_k<1><<<dim3(98, 3), 256, 0, stream>>>(xiR, nullptr, w_out, nullptr,
                                               dT, nullptr, 6272, 192, 384);
    // 10) final: gelu(conv_fina(y2 + x1)) -> out planar (B,96,56,56)
    gemm_k<2><<<dim3(98, 2), 256, 0, stream>>>(dT, x1, w_fina, b_fina,
                                               out, nullptr, 6272, 96, 192);
}